// Round 6
// baseline (173.190 us; speedup 1.0000x reference)
//
#include <hip/hip_runtime.h>
#include <math.h>

#define NS 4
#define SINKHORN_ITERS 10
#define TAU 0.05f

// T*D/4 in float4 units: 4096*2048/4 = 2^21
#define PLANE4 2097152L
#define PLANE4_SHIFT 21
#define NTHREADS (1 << 20)   // 4096 blocks x 256 threads

typedef float f32x4 __attribute__((ext_vector_type(4)));

// ---------------------------------------------------------------------------
// Coefficient math: M[so][si] = Hres[si][so] + ho[so]*hp[si], where Hres is
// sinkhorn_log(H_res_logits) and hp/ho are softmax(H_pre/post_logits).
// Cheap enough (~100 transcendentals) to run redundantly per thread.
// ---------------------------------------------------------------------------
__device__ __forceinline__ void compute_M(const float* __restrict__ Hres_logits,
                                          const float* __restrict__ Hpre_logits,
                                          const float* __restrict__ Hpost_logits,
                                          float* m /*[16]*/) {
    float Z[NS][NS], u[NS], v[NS];
#pragma unroll
    for (int i = 0; i < NS; ++i)
#pragma unroll
        for (int j = 0; j < NS; ++j)
            Z[i][j] = Hres_logits[i * NS + j] / TAU;

    const float logm = -logf((float)NS);
#pragma unroll
    for (int i = 0; i < NS; ++i) { u[i] = 0.f; v[i] = 0.f; }

    for (int it = 0; it < SINKHORN_ITERS; ++it) {
#pragma unroll
        for (int i = 0; i < NS; ++i) {
            float mx = -INFINITY;
#pragma unroll
            for (int j = 0; j < NS; ++j) mx = fmaxf(mx, Z[i][j] + v[j]);
            float s = 0.f;
#pragma unroll
            for (int j = 0; j < NS; ++j) s += expf(Z[i][j] + v[j] - mx);
            u[i] = logm - (mx + logf(s));
        }
#pragma unroll
        for (int j = 0; j < NS; ++j) {
            float mx = -INFINITY;
#pragma unroll
            for (int i = 0; i < NS; ++i) mx = fmaxf(mx, Z[i][j] + u[i]);
            float s = 0.f;
#pragma unroll
            for (int i = 0; i < NS; ++i) s += expf(Z[i][j] + u[i] - mx);
            v[j] = logm - (mx + logf(s));
        }
    }

    float hp[NS], mx = -INFINITY, s = 0.f;
#pragma unroll
    for (int i = 0; i < NS; ++i) mx = fmaxf(mx, Hpre_logits[i]);
#pragma unroll
    for (int i = 0; i < NS; ++i) { hp[i] = expf(Hpre_logits[i] - mx); s += hp[i]; }
#pragma unroll
    for (int i = 0; i < NS; ++i) hp[i] /= s;

    float ho[NS];
    mx = -INFINITY; s = 0.f;
#pragma unroll
    for (int i = 0; i < NS; ++i) mx = fmaxf(mx, Hpost_logits[i]);
#pragma unroll
    for (int i = 0; i < NS; ++i) { ho[i] = expf(Hpost_logits[i] - mx); s += ho[i]; }
#pragma unroll
    for (int i = 0; i < NS; ++i) ho[i] /= s;

#pragma unroll
    for (int so = 0; so < NS; ++so)
#pragma unroll
        for (int si = 0; si < NS; ++si) {
            // exp(Z + u + v) * NS  transposed, plus ho (x) hp
            m[so * NS + si] = expf(Z[si][NS == 0 ? 0 : so] + u[si] + v[so]) * (float)NS
                              + ho[so] * hp[si];
        }
}

// ---------------------------------------------------------------------------
// Fused kernel (fast path): identical memory structure to the best R3 kernel
// (flat unroll-4, NT loads, plain stores, ownership p = gtid + k*2^20).
// All 16 loads issue first; the Sinkhorn/softmax coefficient math runs while
// they are in flight; then 16 FMA+stores.
// ---------------------------------------------------------------------------
__global__ __launch_bounds__(256) void hc_mix_flat(
        const f32x4* __restrict__ in,
        const float* __restrict__ Hres_logits,
        const float* __restrict__ Hpre_logits,
        const float* __restrict__ Hpost_logits,
        f32x4* __restrict__ out) {
    const long gtid = blockIdx.x * blockDim.x + threadIdx.x;

    f32x4 v[4][NS];
#pragma unroll
    for (int k = 0; k < 4; ++k) {
        const long base = (long)(k >> 1) * (NS * PLANE4) + ((long)(k & 1) << 20) + gtid;
#pragma unroll
        for (int s = 0; s < NS; ++s)
            v[k][s] = __builtin_nontemporal_load(&in[base + (long)s * PLANE4]);
    }

    float m[16];
    compute_M(Hres_logits, Hpre_logits, Hpost_logits, m);

#pragma unroll
    for (int k = 0; k < 4; ++k) {
        const long base = (long)(k >> 1) * (NS * PLANE4) + ((long)(k & 1) << 20) + gtid;
#pragma unroll
        for (int o = 0; o < NS; ++o) {
            out[base + (long)o * PLANE4] =
                m[o*4+0] * v[k][0] + m[o*4+1] * v[k][1] +
                m[o*4+2] * v[k][2] + m[o*4+3] * v[k][3];
        }
    }
}

// Generic fallback (any size), same math, coef inlined too.
__global__ __launch_bounds__(256) void hc_mix_generic(
        const f32x4* __restrict__ in,
        const float* __restrict__ Hres_logits,
        const float* __restrict__ Hpre_logits,
        const float* __restrict__ Hpost_logits,
        f32x4* __restrict__ out,
        int npos4) {
    float m[16];
    compute_M(Hres_logits, Hpre_logits, Hpost_logits, m);

    const int stride = gridDim.x * blockDim.x;
    for (int p = blockIdx.x * blockDim.x + threadIdx.x; p < npos4; p += stride) {
        const int b = p >> PLANE4_SHIFT;
        const long base = ((long)(b * NS) << PLANE4_SHIFT) + (p & (PLANE4 - 1));
        const f32x4 v0 = in[base];
        const f32x4 v1 = in[base + PLANE4];
        const f32x4 v2 = in[base + 2 * PLANE4];
        const f32x4 v3 = in[base + 3 * PLANE4];
#pragma unroll
        for (int o = 0; o < NS; ++o)
            out[base + (long)o * PLANE4] =
                m[o*4+0]*v0 + m[o*4+1]*v1 + m[o*4+2]*v2 + m[o*4+3]*v3;
    }
}

extern "C" void kernel_launch(void* const* d_in, const int* in_sizes, int n_in,
                              void* d_out, int out_size, void* d_ws, size_t ws_size,
                              hipStream_t stream) {
    const float* residuals   = (const float*)d_in[0];  // (B*S, T, D) = (8,4096,2048) f32
    const float* Hres_logits = (const float*)d_in[1];  // (4,4)
    const float* Hpre_logits = (const float*)d_in[2];  // (4,)
    const float* Hpost_logits= (const float*)d_in[3];  // (4,)
    float* out = (float*)d_out;

    const int npos4 = out_size / (NS * 4);             // B*T*D/4 = 4194304
    if (npos4 == 4 * NTHREADS) {
        hc_mix_flat<<<NTHREADS / 256, 256, 0, stream>>>(
            (const f32x4*)residuals, Hres_logits, Hpre_logits, Hpost_logits,
            (f32x4*)out);
    } else {
        hc_mix_generic<<<2048, 256, 0, stream>>>(
            (const f32x4*)residuals, Hres_logits, Hpre_logits, Hpost_logits,
            (f32x4*)out, npos4);
    }
}

// Round 7
// 110.070 us; speedup vs baseline: 1.5735x; 1.5735x over previous
//
#include <hip/hip_runtime.h>
#include <math.h>

#define NS 4
#define SINKHORN_ITERS 10
#define TAU 0.05f

// T*D/4 in float4 units: 4096*2048/4 = 2^21
#define PLANE4 2097152L
#define PLANE4_SHIFT 21
#define NTHREADS (1 << 20)   // 4096 blocks x 256 threads

typedef float f32x4 __attribute__((ext_vector_type(4)));

// ---------------------------------------------------------------------------
// Kernel 1: compute M[4][4] = H_res^T + H_post (outer) H_pre  into d_ws.
// One thread; ~100 transcendentals. Runs once, overlaps launch of kernel 2.
// ---------------------------------------------------------------------------
__global__ void hc_coef_kernel(const float* __restrict__ Hres_logits,
                               const float* __restrict__ Hpre_logits,
                               const float* __restrict__ Hpost_logits,
                               float* __restrict__ M) {
    if (threadIdx.x != 0 || blockIdx.x != 0) return;

    float Z[NS][NS], u[NS], v[NS];
    for (int i = 0; i < NS; ++i)
        for (int j = 0; j < NS; ++j)
            Z[i][j] = Hres_logits[i * NS + j] / TAU;

    const float logm = -logf((float)NS);
    for (int i = 0; i < NS; ++i) { u[i] = 0.f; v[i] = 0.f; }

    for (int it = 0; it < SINKHORN_ITERS; ++it) {
        for (int i = 0; i < NS; ++i) {
            float mx = -INFINITY;
            for (int j = 0; j < NS; ++j) mx = fmaxf(mx, Z[i][j] + v[j]);
            float s = 0.f;
            for (int j = 0; j < NS; ++j) s += expf(Z[i][j] + v[j] - mx);
            u[i] = logm - (mx + logf(s));
        }
        for (int j = 0; j < NS; ++j) {
            float mx = -INFINITY;
            for (int i = 0; i < NS; ++i) mx = fmaxf(mx, Z[i][j] + u[i]);
            float s = 0.f;
            for (int i = 0; i < NS; ++i) s += expf(Z[i][j] + u[i] - mx);
            v[j] = logm - (mx + logf(s));
        }
    }

    float Hres[NS][NS];
    for (int i = 0; i < NS; ++i)
        for (int j = 0; j < NS; ++j)
            Hres[i][j] = expf(Z[i][j] + u[i] + v[j]) * (float)NS;

    float hp[NS], mx = -INFINITY, s = 0.f;
    for (int i = 0; i < NS; ++i) mx = fmaxf(mx, Hpre_logits[i]);
    for (int i = 0; i < NS; ++i) { hp[i] = expf(Hpre_logits[i] - mx); s += hp[i]; }
    for (int i = 0; i < NS; ++i) hp[i] /= s;

    float ho[NS];
    mx = -INFINITY; s = 0.f;
    for (int i = 0; i < NS; ++i) mx = fmaxf(mx, Hpost_logits[i]);
    for (int i = 0; i < NS; ++i) { ho[i] = expf(Hpost_logits[i] - mx); s += ho[i]; }
    for (int i = 0; i < NS; ++i) ho[i] /= s;

    for (int so = 0; so < NS; ++so)
        for (int si = 0; si < NS; ++si)
            M[so * NS + si] = Hres[si][so] + ho[so] * hp[si];
}

// ---------------------------------------------------------------------------
// Kernel 2 (fast path): R3 structure — flat unroll-4, 2^20 threads, thread t
// owns positions t + k*2^20 (k=0..3; b = k>>1 compile-time).
// Cache policy: PLAIN loads (let the 256MB input become L3-resident),
// NONTEMPORAL stores (write stream bypasses, doesn't evict the input).
// ---------------------------------------------------------------------------
__global__ __launch_bounds__(256) void hc_mix_flat(
        const f32x4* __restrict__ in,
        const float* __restrict__ Mg,
        f32x4* __restrict__ out) {
    float m[16];
#pragma unroll
    for (int k = 0; k < 16; ++k) m[k] = Mg[k];

    const long gtid = blockIdx.x * blockDim.x + threadIdx.x;

    f32x4 v[4][NS];
#pragma unroll
    for (int k = 0; k < 4; ++k) {
        const long base = (long)(k >> 1) * (NS * PLANE4) + ((long)(k & 1) << 20) + gtid;
#pragma unroll
        for (int s = 0; s < NS; ++s)
            v[k][s] = in[base + (long)s * PLANE4];
    }

#pragma unroll
    for (int k = 0; k < 4; ++k) {
        const long base = (long)(k >> 1) * (NS * PLANE4) + ((long)(k & 1) << 20) + gtid;
#pragma unroll
        for (int o = 0; o < NS; ++o) {
            f32x4 r = m[o*4+0] * v[k][0] + m[o*4+1] * v[k][1] +
                      m[o*4+2] * v[k][2] + m[o*4+3] * v[k][3];
            __builtin_nontemporal_store(r, &out[base + (long)o * PLANE4]);
        }
    }
}

// Generic fallback (any size), same math.
__global__ __launch_bounds__(256) void hc_mix_generic(
        const f32x4* __restrict__ in,
        const float* __restrict__ Mg,
        f32x4* __restrict__ out,
        int npos4) {
    float m[16];
#pragma unroll
    for (int k = 0; k < 16; ++k) m[k] = Mg[k];

    const int stride = gridDim.x * blockDim.x;
    for (int p = blockIdx.x * blockDim.x + threadIdx.x; p < npos4; p += stride) {
        const int b = p >> PLANE4_SHIFT;
        const long base = ((long)(b * NS) << PLANE4_SHIFT) + (p & (PLANE4 - 1));
        const f32x4 v0 = in[base];
        const f32x4 v1 = in[base + PLANE4];
        const f32x4 v2 = in[base + 2 * PLANE4];
        const f32x4 v3 = in[base + 3 * PLANE4];
#pragma unroll
        for (int o = 0; o < NS; ++o) {
            f32x4 r = m[o*4+0]*v0 + m[o*4+1]*v1 + m[o*4+2]*v2 + m[o*4+3]*v3;
            __builtin_nontemporal_store(r, &out[base + (long)o * PLANE4]);
        }
    }
}

extern "C" void kernel_launch(void* const* d_in, const int* in_sizes, int n_in,
                              void* d_out, int out_size, void* d_ws, size_t ws_size,
                              hipStream_t stream) {
    const float* residuals   = (const float*)d_in[0];  // (B*S, T, D) = (8,4096,2048) f32
    const float* Hres_logits = (const float*)d_in[1];  // (4,4)
    const float* Hpre_logits = (const float*)d_in[2];  // (4,)
    const float* Hpost_logits= (const float*)d_in[3];  // (4,)
    float* out = (float*)d_out;
    float* M   = (float*)d_ws;                         // 16 floats

    hc_coef_kernel<<<1, 64, 0, stream>>>(Hres_logits, Hpre_logits, Hpost_logits, M);

    const int npos4 = out_size / (NS * 4);             // B*T*D/4 = 4194304
    if (npos4 == 4 * NTHREADS) {
        hc_mix_flat<<<NTHREADS / 256, 256, 0, stream>>>(
            (const f32x4*)residuals, M, (f32x4*)out);
    } else {
        hc_mix_generic<<<2048, 256, 0, stream>>>(
            (const f32x4*)residuals, M, (f32x4*)out, npos4);
    }
}